// Round 22
// baseline (100.807 us; speedup 1.0000x reference)
//
#include <hip/hip_runtime.h>
#include <math.h>

#define B_ 64
#define IC 2048
#define OC 32
#define OD 16
#define ID 8

typedef __attribute__((ext_vector_type(8)))  short s16x8;
typedef __attribute__((ext_vector_type(16))) float f32x16;

__device__ __forceinline__ unsigned short f2bf(float f) {      // RNE f32->bf16
  unsigned u = __float_as_uint(f);
  return (unsigned short)((u + 0x7fffu + ((u >> 16) & 1u)) >> 16);
}
__device__ __forceinline__ float bf2f(unsigned short h) {
  return __uint_as_float(((unsigned)h) << 16);
}
__device__ __forceinline__ f32x16 mfma16(s16x8 a, s16x8 b, f32x16 c) {
  return __builtin_amdgcn_mfma_f32_32x32x16_bf16(a, b, c, 0, 0, 0);
}

// ---------------------------------------------------------------------------
// One-time split-bf16 conversion, W and x merged in ONE launch (proven R20).
// Wbf: [i][half][o][d][m] ushort; xb: [i][half][b][m] ushort.
// ---------------------------------------------------------------------------
__global__ __launch_bounds__(256) void convWX(
    const float* __restrict__ W, const float* __restrict__ x,
    unsigned short* __restrict__ Wbf, unsigned short* __restrict__ xb)
{
  const int bid = blockIdx.x;
  if (bid < 8192) {
    const int e4 = bid * 256 + threadIdx.x;
    const float4 v = ((const float4*)W)[e4];
    const int i = e4 >> 10;
    const int r = (e4 & 1023) << 2;
    ushort4 h, l;
    h.x = f2bf(v.x); l.x = f2bf(v.x - bf2f(h.x));
    h.y = f2bf(v.y); l.y = f2bf(v.y - bf2f(h.y));
    h.z = f2bf(v.z); l.z = f2bf(v.z - bf2f(h.z));
    h.w = f2bf(v.w); l.w = f2bf(v.w - bf2f(h.w));
    *(ushort4*)&Wbf[(size_t)i * 8192 + r]        = h;
    *(ushort4*)&Wbf[(size_t)i * 8192 + 4096 + r] = l;
  } else {
    const int idx = (bid - 8192) * 256 + threadIdx.x;
    const int m2 = idx & 1, i = (idx >> 1) & 2047, b = idx >> 12;
    const float4 v = *(const float4*)(x + (size_t)b * 16384 + i * 8 + m2 * 4);
    ushort4 h, l;
    h.x = f2bf(v.x); l.x = f2bf(v.x - bf2f(h.x));
    h.y = f2bf(v.y); l.y = f2bf(v.y - bf2f(h.y));
    h.z = f2bf(v.z); l.z = f2bf(v.z - bf2f(h.z));
    h.w = f2bf(v.w); l.w = f2bf(v.w - bf2f(h.w));
    *(ushort4*)&xb[(size_t)i * 1024 + b * 8 + m2 * 4]       = h;
    *(ushort4*)&xb[(size_t)i * 1024 + 512 + b * 8 + m2 * 4] = l;
  }
}

// ---------------------------------------------------------------------------
// MFMA routing pass (R16 body, proven): no LDS, no barriers; vs scrambled;
// depth-2 prefetch via 3 rotating register stages (lowest-VGPR config ~80 ->
// 6 waves/SIMD cap). R22 runs it at NCH=256: grid 2048 = 8 blocks/CU target,
// removing the 4-blocks/CU grid cap that Little's-law analysis identified as
// the fusedM limiter (waves x in-flight-loads bound, not BW).
// bid = q*NCH + ch (NCH%8==0 -> same-ch blocks on one XCD).
// ---------------------------------------------------------------------------
template<bool WEIGHTED, int NCH>
__global__ __launch_bounds__(256) void fusedM(
    const unsigned short* __restrict__ Wbf, const unsigned short* __restrict__ xb,
    const float* __restrict__ vss, float* __restrict__ part,
    float* __restrict__ zpart)
{
  constexpr int CI = IC / NCH;
  const int t     = threadIdx.x;
  const int ch    = blockIdx.x % NCH;
  const int q     = blockIdx.x / NCH;
  const int lane  = t & 63;
  const int wv    = t >> 6;
  const int s     = q * 4 + wv;          // 0..31
  const int opair = s >> 1;
  const int bt    = s & 1;
  const int l31   = lane & 31;
  const int hb    = lane >> 5;
  const int i0    = ch * CI;

  const unsigned short* ap =
      Wbf + (size_t)i0 * 8192 + opair * 256 + (l31 >> 4) * 128 + (lane & 15) * 8;
  const unsigned short* bp =
      xb + (size_t)i0 * 1024 + hb * 512 + bt * 256 + l31 * 8;

  f32x16 acc = (f32x16)0.0f;
  float zA = 0.f, zB = 0.f;
  float vsr[16];

  if constexpr (WEIGHTED) {
    const float* vp = vss + s * 1024 + hb * 32 + l31;   // coalesced 256B/ld
#pragma unroll
    for (int r = 0; r < 16; ++r) vsr[r] = vp[r * 64];
  }

  s16x8 AH[3], AL[3], BV[3];
  AH[0] = *(const s16x8*)ap;
  AL[0] = *(const s16x8*)(ap + 4096);
  BV[0] = *(const s16x8*)bp;
  if (CI > 1) {
    AH[1] = *(const s16x8*)(ap + 8192);
    AL[1] = *(const s16x8*)(ap + 8192 + 4096);
    BV[1] = *(const s16x8*)(bp + 1024);
  }

#pragma unroll
  for (int ii = 0; ii < CI; ++ii) {
    const int cs = ii % 3;
    const int ns = (ii + 2) % 3;
    if (ii + 2 < CI) {                       // issue 2 iters ahead
      AH[ns] = *(const s16x8*)(ap + (size_t)(ii + 2) * 8192);
      AL[ns] = *(const s16x8*)(ap + (size_t)(ii + 2) * 8192 + 4096);
      BV[ns] = *(const s16x8*)(bp + (size_t)(ii + 2) * 1024);
    }

    if constexpr (!WEIGHTED) {
      acc = mfma16(AH[cs], BV[cs], acc);
      acc = mfma16(AL[cs], BV[cs], acc);
    } else {
      f32x16 u = mfma16(AH[cs], BV[cs], (f32x16)0.0f);
      u = mfma16(AL[cs], BV[cs], u);
      float pdA = 0.f, pdB = 0.f;
#pragma unroll
      for (int r = 0; r < 8; ++r)  pdA = fmaf(u[r], vsr[r], pdA);
#pragma unroll
      for (int r = 8; r < 16; ++r) pdB = fmaf(u[r], vsr[r], pdB);
      pdA += __shfl_xor(pdA, 32);            // add other hb's 8 d's
      pdB += __shfl_xor(pdB, 32);
      const float pA = __expf(pdA), pB = __expf(pdB);
#pragma unroll
      for (int r = 0; r < 8; ++r)  acc[r] = fmaf(pA, u[r], acc[r]);
#pragma unroll
      for (int r = 8; r < 16; ++r) acc[r] = fmaf(pB, u[r], acc[r]);
      zA += pA; zB += pB;
    }
  }

  // scrambled, coalesced epilogue
  float* op = part + (size_t)ch * 32768;
#pragma unroll
  for (int r = 0; r < 16; ++r)
    op[(s * 16 + r) * 64 + hb * 32 + l31] = acc[r];
  if constexpr (WEIGHTED) {
    if (lane < 32) {
      zpart[(size_t)ch * 2048 + (s * 2 + 0) * 32 + lane] = zA;
      zpart[(size_t)ch * 2048 + (s * 2 + 1) * 32 + lane] = zB;
    }
  }
}

// ---------------------------------------------------------------------------
// Two-stage reduction (R22). Stage A: 1024 blocks x 512; block (g, sl) sums
// chs [g*CPG, (g+1)*CPG) over slice sl of the scrambled part -> pp2[16][32768]
// (fully parallel, coalesced). sl==0 blocks also fold zpart -> zp2[16][2048].
// ---------------------------------------------------------------------------
template<bool WEIGHTED, int NCH>
__global__ __launch_bounds__(512) void rsqA(
    const float* __restrict__ part, const float* __restrict__ zpart,
    float* __restrict__ pp2, float* __restrict__ zp2)
{
  constexpr int CPG = NCH / 16;
  const int t  = threadIdx.x;
  const int g  = blockIdx.x >> 6;
  const int sl = blockIdx.x & 63;
  const size_t tid = (size_t)sl * 512 + t;

  float acc = 0.f;
#pragma unroll 8
  for (int c = 0; c < CPG; ++c)
    acc += part[(size_t)(g * CPG + c) * 32768 + tid];
  pp2[(size_t)g * 32768 + tid] = acc;

  if constexpr (WEIGHTED) {
    if (sl == 0) {
#pragma unroll
      for (int k = 0; k < 4; ++k) {
        const int j = t + 512 * k;
        float zs = 0.f;
#pragma unroll 8
        for (int c = 0; c < CPG; ++c)
          zs += zpart[(size_t)(g * CPG + c) * 2048 + j];
        zp2[(size_t)g * 2048 + j] = zs;
      }
    }
  }
}

// ---------------------------------------------------------------------------
// Stage B: reduce the 16 group-partials + normalize + squash (R16 rsqM body
// with the ch-loop shrunk to 16 groups). vss kept scrambled; PASS 2 writes
// standard-layout out. grid 64 x 512.
// ---------------------------------------------------------------------------
template<int PASS>
__global__ __launch_bounds__(512) void rsqB(
    const float* __restrict__ pp2, const float* __restrict__ zp2,
    float* __restrict__ vss, float* __restrict__ out)
{
  __shared__ float rzs[32];
  __shared__ float sqs[512];
  const int t   = threadIdx.x;
  const int blk = blockIdx.x;
  const int s   = blk >> 1, oo = blk & 1;
  const int l31 = t & 31, hb = (t >> 5) & 1, rr = t >> 6;
  const size_t tid = (size_t)blk * 512 + t;

  float acc = 0.f;
#pragma unroll
  for (int g = 0; g < 16; ++g) acc += pp2[(size_t)g * 32768 + tid];

  if constexpr (PASS == 0) {
    if (t < 32) rzs[t] = 1.f / 2048.f;
  } else {
    if (t < 32) {
      float zs = 0.f;
#pragma unroll
      for (int g = 0; g < 16; ++g)
        zs += zp2[(size_t)g * 2048 + (s * 2 + oo) * 32 + t];
      rzs[t] = 1.f / zs;
    }
  }
  __syncthreads();
  const float sv = acc * rzs[l31];
  sqs[t] = sv * sv;
  __syncthreads();
  float sq = 0.f;
#pragma unroll
  for (int k = 0; k < 16; ++k) sq += sqs[l31 + k * 32];
  const float f = (sq / (1.f + sq)) * rsqrtf(sq + 1e-9f);
  const float v = sv * f;

  if constexpr (PASS == 0)      vss[tid] = v;
  else if constexpr (PASS == 1) vss[tid] += v;
  else {
    const int b = (s & 1) * 32 + l31;
    const int o = (s >> 1) * 2 + oo;
    const int d = (rr & 3) + 8 * (rr >> 2) + 4 * hb;
    out[(b * 32 + o) * 16 + d] = v;
  }
}

// ---------------------------------------------------------------------------
// Single-stage reducer (R20 rsqM, proven) for the NCH=128 fallback path.
// ---------------------------------------------------------------------------
template<int PASS, int NCH>
__global__ __launch_bounds__(512) void rsqM(
    const float* __restrict__ part, const float* __restrict__ zpart,
    float* __restrict__ vss, float* __restrict__ out)
{
  __shared__ float rzs[32];
  __shared__ float sqs[512];
  const int t   = threadIdx.x;
  const int blk = blockIdx.x;
  const int s   = blk >> 1, oo = blk & 1;
  const int l31 = t & 31, hb = (t >> 5) & 1, rr = t >> 6;
  const size_t tid = (size_t)blk * 512 + t;

  float acc = 0.f;
#pragma unroll 8
  for (int ch = 0; ch < NCH; ++ch) acc += part[(size_t)ch * 32768 + tid];

  if constexpr (PASS == 0) {
    if (t < 32) rzs[t] = 1.f / 2048.f;
  } else {
    if (t < 32) {
      float zs = 0.f;
#pragma unroll 8
      for (int ch = 0; ch < NCH; ++ch)
        zs += zpart[(size_t)ch * 2048 + (s * 2 + oo) * 32 + t];
      rzs[t] = 1.f / zs;
    }
  }
  __syncthreads();
  const float sv = acc * rzs[l31];
  sqs[t] = sv * sv;
  __syncthreads();
  float sq = 0.f;
#pragma unroll
  for (int k = 0; k < 16; ++k) sq += sqs[l31 + k * 32];
  const float f = (sq / (1.f + sq)) * rsqrtf(sq + 1e-9f);
  const float v = sv * f;

  if constexpr (PASS == 0)      vss[tid] = v;
  else if constexpr (PASS == 1) vss[tid] += v;
  else {
    const int b = (s & 1) * 32 + l31;
    const int o = (s >> 1) * 2 + oo;
    const int d = (rr & 3) + 8 * (rr >> 2) + 4 * hb;
    out[(b * 32 + o) * 16 + d] = v;
  }
}

// ---------------------------------------------------------------------------
extern "C" void kernel_launch(void* const* d_in, const int* in_sizes, int n_in,
                              void* d_out, int out_size, void* d_ws, size_t ws_size,
                              hipStream_t stream) {
  (void)in_sizes; (void)n_in; (void)out_size;
  const float* x = (const float*)d_in[0];
  const float* W = (const float*)d_in[1];
  float* out = (float*)d_out;
  float* ws  = (float*)d_ws;

  const size_t WBF_US = (size_t)IC * 8192;
  const size_t XB_US  = (size_t)IC * 1024;

  // ---- primary path: NCH=256 fusedM + two-stage reduce ----
  const size_t need256 =
      ((size_t)256 * 32768 + 256ul * 2048 + 16ul * 32768 + 16ul * 2048 + 32768) * 4
      + (WBF_US + XB_US) * 2;
  // ---- fallback path: NCH=128 + single-stage (R20, proven 95.3us) ----
  const size_t need128 =
      ((size_t)128 * 32768 + 128ul * 2048 + 32768) * 4 + (WBF_US + XB_US) * 2;

  if (ws_size >= need256) {
    constexpr int NCH = 256;
    float* part  = ws;                                  // [256][32768]
    float* zpart = part + (size_t)NCH * 32768;          // [256][2048]
    float* pp2   = zpart + (size_t)NCH * 2048;          // [16][32768]
    float* zp2   = pp2 + 16ul * 32768;                  // [16][2048]
    float* vsb   = zp2 + 16ul * 2048;                   // [32768] scrambled vs
    unsigned short* Wbf = (unsigned short*)(vsb + 32768);
    unsigned short* xbp = Wbf + WBF_US;

    const dim3 b256(256), b512(512), gF(8 * NCH), gA(1024), gB(64);
    convWX<<<dim3(9216), b256, 0, stream>>>(W, x, Wbf, xbp);
    // pass 1: uniform c -> v1
    fusedM<false, NCH><<<gF, b256, 0, stream>>>(Wbf, xbp, nullptr, part, nullptr);
    rsqA<false, NCH><<<gA, b512, 0, stream>>>(part, nullptr, pp2, nullptr);
    rsqB<0><<<gB, b512, 0, stream>>>(pp2, nullptr, vsb, nullptr);
    // pass 2: p = exp(u.v1) -> v2; vs = v1+v2
    fusedM<true, NCH><<<gF, b256, 0, stream>>>(Wbf, xbp, vsb, part, zpart);
    rsqA<true, NCH><<<gA, b512, 0, stream>>>(part, zpart, pp2, zp2);
    rsqB<1><<<gB, b512, 0, stream>>>(pp2, zp2, vsb, nullptr);
    // pass 3: p = exp(u.(v1+v2)) -> v3 = out
    fusedM<true, NCH><<<gF, b256, 0, stream>>>(Wbf, xbp, vsb, part, zpart);
    rsqA<true, NCH><<<gA, b512, 0, stream>>>(part, zpart, pp2, zp2);
    rsqB<2><<<gB, b512, 0, stream>>>(pp2, zp2, nullptr, out);
    return;
  }

  {
    constexpr int NCH = 128;
    float* part  = ws;
    float* zpart = part + (size_t)NCH * 32768;
    float* vsb   = zpart + (size_t)NCH * 2048;
    unsigned short* Wbf = (unsigned short*)(vsb + 32768);
    unsigned short* xbp = Wbf + WBF_US;
    (void)need128;

    const dim3 b256(256), b512(512), gF(8 * NCH), gR(64);
    convWX<<<dim3(9216), b256, 0, stream>>>(W, x, Wbf, xbp);
    fusedM<false, NCH><<<gF, b256, 0, stream>>>(Wbf, xbp, nullptr, part, nullptr);
    rsqM<0, NCH><<<gR, b512, 0, stream>>>(part, nullptr, vsb, nullptr);
    fusedM<true, NCH><<<gF, b256, 0, stream>>>(Wbf, xbp, vsb, part, zpart);
    rsqM<1, NCH><<<gR, b512, 0, stream>>>(part, zpart, vsb, nullptr);
    fusedM<true, NCH><<<gF, b256, 0, stream>>>(Wbf, xbp, vsb, part, zpart);
    rsqM<2, NCH><<<gR, b512, 0, stream>>>(part, zpart, nullptr, out);
  }
}

// Round 23
// 95.476 us; speedup vs baseline: 1.0558x; 1.0558x over previous
//
#include <hip/hip_runtime.h>
#include <math.h>

#define B_ 64
#define IC 2048
#define OC 32
#define OD 16
#define ID 8

typedef __attribute__((ext_vector_type(8)))  short s16x8;
typedef __attribute__((ext_vector_type(16))) float f32x16;

__device__ __forceinline__ unsigned short f2bf(float f) {      // RNE f32->bf16
  unsigned u = __float_as_uint(f);
  return (unsigned short)((u + 0x7fffu + ((u >> 16) & 1u)) >> 16);
}
__device__ __forceinline__ float bf2f(unsigned short h) {
  return __uint_as_float(((unsigned)h) << 16);
}
__device__ __forceinline__ f32x16 mfma16(s16x8 a, s16x8 b, f32x16 c) {
  return __builtin_amdgcn_mfma_f32_32x32x16_bf16(a, b, c, 0, 0, 0);
}

// ---------------------------------------------------------------------------
// One-time split-bf16 conversion, W and x merged into ONE launch (R20,
// proven): blocks [0,8192) convert W, blocks [8192,9216) convert x.
// Wbf: [i][half][o][d][m] ushort; xb: [i][half][b][m] ushort.
// This kernel runs at the HBM roofline for its ~75MB round trip (~13us).
// ---------------------------------------------------------------------------
__global__ __launch_bounds__(256) void convWX(
    const float* __restrict__ W, const float* __restrict__ x,
    unsigned short* __restrict__ Wbf, unsigned short* __restrict__ xb)
{
  const int bid = blockIdx.x;
  if (bid < 8192) {
    const int e4 = bid * 256 + threadIdx.x;
    const float4 v = ((const float4*)W)[e4];
    const int i = e4 >> 10;
    const int r = (e4 & 1023) << 2;
    ushort4 h, l;
    h.x = f2bf(v.x); l.x = f2bf(v.x - bf2f(h.x));
    h.y = f2bf(v.y); l.y = f2bf(v.y - bf2f(h.y));
    h.z = f2bf(v.z); l.z = f2bf(v.z - bf2f(h.z));
    h.w = f2bf(v.w); l.w = f2bf(v.w - bf2f(h.w));
    *(ushort4*)&Wbf[(size_t)i * 8192 + r]        = h;
    *(ushort4*)&Wbf[(size_t)i * 8192 + 4096 + r] = l;
  } else {
    const int idx = (bid - 8192) * 256 + threadIdx.x;
    const int m2 = idx & 1, i = (idx >> 1) & 2047, b = idx >> 12;
    const float4 v = *(const float4*)(x + (size_t)b * 16384 + i * 8 + m2 * 4);
    ushort4 h, l;
    h.x = f2bf(v.x); l.x = f2bf(v.x - bf2f(h.x));
    h.y = f2bf(v.y); l.y = f2bf(v.y - bf2f(h.y));
    h.z = f2bf(v.z); l.z = f2bf(v.z - bf2f(h.z));
    h.w = f2bf(v.w); l.w = f2bf(v.w - bf2f(h.w));
    *(ushort4*)&xb[(size_t)i * 1024 + b * 8 + m2 * 4]       = h;
    *(ushort4*)&xb[(size_t)i * 1024 + 512 + b * 8 + m2 * 4] = l;
  }
}

// ---------------------------------------------------------------------------
// MFMA routing pass (R16/R20, proven best): no LDS, no barriers; vs in
// scrambled layout (coalesced 256B loads); depth-2 prefetch via 3 rotating
// register stages (all indices compile-time under full unroll).
// grid = 8*NCH, bid = q*NCH + ch (NCH%8==0 -> same-ch blocks on one XCD).
// wave slot s = q*4+wv: opair = s>>1, bt = s&1; one 32x32 tile per wave.
// part/zpart stored in MFMA-register ("scrambled") order: coalesced stores.
// Falsified levers for the ~20us/pass wall: depth-4 prefetch (R21 null),
// more waves via NCH=256 (R18/R22 regression), convFused x-scatter (R17).
// ---------------------------------------------------------------------------
template<bool WEIGHTED, int NCH>
__global__ __launch_bounds__(256) void fusedM(
    const unsigned short* __restrict__ Wbf, const unsigned short* __restrict__ xb,
    const float* __restrict__ vss, float* __restrict__ part,
    float* __restrict__ zpart)
{
  constexpr int CI = IC / NCH;
  const int t     = threadIdx.x;
  const int ch    = blockIdx.x % NCH;
  const int q     = blockIdx.x / NCH;
  const int lane  = t & 63;
  const int wv    = t >> 6;
  const int s     = q * 4 + wv;          // 0..31
  const int opair = s >> 1;
  const int bt    = s & 1;
  const int l31   = lane & 31;
  const int hb    = lane >> 5;
  const int i0    = ch * CI;

  const unsigned short* ap =
      Wbf + (size_t)i0 * 8192 + opair * 256 + (l31 >> 4) * 128 + (lane & 15) * 8;
  const unsigned short* bp =
      xb + (size_t)i0 * 1024 + hb * 512 + bt * 256 + l31 * 8;

  f32x16 acc = (f32x16)0.0f;
  float zA = 0.f, zB = 0.f;
  float vsr[16];

  if constexpr (WEIGHTED) {
    const float* vp = vss + s * 1024 + hb * 32 + l31;   // coalesced 256B/ld
#pragma unroll
    for (int r = 0; r < 16; ++r) vsr[r] = vp[r * 64];
  }

  s16x8 AH[3], AL[3], BV[3];
  AH[0] = *(const s16x8*)ap;
  AL[0] = *(const s16x8*)(ap + 4096);
  BV[0] = *(const s16x8*)bp;
  if (CI > 1) {
    AH[1] = *(const s16x8*)(ap + 8192);
    AL[1] = *(const s16x8*)(ap + 8192 + 4096);
    BV[1] = *(const s16x8*)(bp + 1024);
  }

#pragma unroll
  for (int ii = 0; ii < CI; ++ii) {
    const int cs = ii % 3;
    const int ns = (ii + 2) % 3;
    if (ii + 2 < CI) {                       // issue 2 iters ahead
      AH[ns] = *(const s16x8*)(ap + (size_t)(ii + 2) * 8192);
      AL[ns] = *(const s16x8*)(ap + (size_t)(ii + 2) * 8192 + 4096);
      BV[ns] = *(const s16x8*)(bp + (size_t)(ii + 2) * 1024);
    }

    if constexpr (!WEIGHTED) {
      acc = mfma16(AH[cs], BV[cs], acc);
      acc = mfma16(AL[cs], BV[cs], acc);
    } else {
      f32x16 u = mfma16(AH[cs], BV[cs], (f32x16)0.0f);
      u = mfma16(AL[cs], BV[cs], u);
      float pdA = 0.f, pdB = 0.f;
#pragma unroll
      for (int r = 0; r < 8; ++r)  pdA = fmaf(u[r], vsr[r], pdA);
#pragma unroll
      for (int r = 8; r < 16; ++r) pdB = fmaf(u[r], vsr[r], pdB);
      pdA += __shfl_xor(pdA, 32);            // add other hb's 8 d's
      pdB += __shfl_xor(pdB, 32);
      const float pA = __expf(pdA), pB = __expf(pdB);
#pragma unroll
      for (int r = 0; r < 8; ++r)  acc[r] = fmaf(pA, u[r], acc[r]);
#pragma unroll
      for (int r = 8; r < 16; ++r) acc[r] = fmaf(pB, u[r], acc[r]);
      zA += pA; zB += pB;
    }
  }

  // scrambled, coalesced epilogue
  float* op = part + (size_t)ch * 32768;
#pragma unroll
  for (int r = 0; r < 16; ++r)
    op[(s * 16 + r) * 64 + hb * 32 + l31] = acc[r];
  if constexpr (WEIGHTED) {
    if (lane < 32) {
      zpart[(size_t)ch * 2048 + (s * 2 + 0) * 32 + lane] = zA;
      zpart[(size_t)ch * 2048 + (s * 2 + 1) * 32 + lane] = zB;
    }
  }
}

// ---------------------------------------------------------------------------
// Reduce+squash over scrambled part; vss kept scrambled (coalesced both
// directions); PASS 2 writes standard-layout out. grid 64 x 512.
// ---------------------------------------------------------------------------
template<int PASS, int NCH>
__global__ __launch_bounds__(512) void rsqM(
    const float* __restrict__ part, const float* __restrict__ zpart,
    float* __restrict__ vss, float* __restrict__ out)
{
  __shared__ float rzs[32];
  __shared__ float sqs[512];
  const int t   = threadIdx.x;
  const int blk = blockIdx.x;
  const int s   = blk >> 1, oo = blk & 1;
  const int l31 = t & 31, hb = (t >> 5) & 1, rr = t >> 6;
  const size_t tid = (size_t)blk * 512 + t;

  float acc = 0.f;
#pragma unroll 8
  for (int ch = 0; ch < NCH; ++ch) acc += part[(size_t)ch * 32768 + tid];

  if constexpr (PASS == 0) {
    if (t < 32) rzs[t] = 1.f / 2048.f;
  } else {
    if (t < 32) {
      float zs = 0.f;
#pragma unroll 8
      for (int ch = 0; ch < NCH; ++ch)
        zs += zpart[(size_t)ch * 2048 + (s * 2 + oo) * 32 + t];
      rzs[t] = 1.f / zs;
    }
  }
  __syncthreads();
  const float sv = acc * rzs[l31];
  sqs[t] = sv * sv;
  __syncthreads();
  float sq = 0.f;
#pragma unroll
  for (int k = 0; k < 16; ++k) sq += sqs[l31 + k * 32];
  const float f = (sq / (1.f + sq)) * rsqrtf(sq + 1e-9f);
  const float v = sv * f;

  if constexpr (PASS == 0)      vss[tid] = v;
  else if constexpr (PASS == 1) vss[tid] += v;
  else {
    const int b = (s & 1) * 32 + l31;
    const int o = (s >> 1) * 2 + oo;
    const int d = (rr & 3) + 8 * (rr >> 2) + 4 * hb;
    out[(b * 32 + o) * 16 + d] = v;
  }
}

// ---------------------------------------------------------------------------
extern "C" void kernel_launch(void* const* d_in, const int* in_sizes, int n_in,
                              void* d_out, int out_size, void* d_ws, size_t ws_size,
                              hipStream_t stream) {
  (void)in_sizes; (void)n_in; (void)out_size;
  const float* x = (const float*)d_in[0];
  const float* W = (const float*)d_in[1];
  float* out = (float*)d_out;
  float* ws  = (float*)d_ws;

  const size_t WBF_US = (size_t)IC * 8192;
  const size_t XB_US  = (size_t)IC * 1024;

  auto runM = [&](auto tag) {
    constexpr int NCH = decltype(tag)::value;
    float* part  = ws;                                  // [NCH][32768] scrambled
    float* zpart = part + (size_t)NCH * 32768;          // [NCH][2048] scrambled
    float* vsb   = zpart + (size_t)NCH * 2048;          // [32768] scrambled vs
    unsigned short* Wbf = (unsigned short*)(vsb + 32768);
    unsigned short* xbp = Wbf + WBF_US;

    const dim3 b256(256), b512(512), gF(8 * NCH), gR(64);
    // conversions (merged single launch)
    convWX<<<dim3(9216), b256, 0, stream>>>(W, x, Wbf, xbp);
    // pass 1: uniform c -> v1
    fusedM<false, NCH><<<gF, b256, 0, stream>>>(Wbf, xbp, nullptr, part, nullptr);
    rsqM<0, NCH><<<gR, b512, 0, stream>>>(part, nullptr, vsb, nullptr);
    // pass 2: p = exp(u.v1) -> v2; vs = v1+v2
    fusedM<true, NCH><<<gF, b256, 0, stream>>>(Wbf, xbp, vsb, part, zpart);
    rsqM<1, NCH><<<gR, b512, 0, stream>>>(part, zpart, vsb, nullptr);
    // pass 3: p = exp(u.(v1+v2)) -> v3 = out
    fusedM<true, NCH><<<gF, b256, 0, stream>>>(Wbf, xbp, vsb, part, zpart);
    rsqM<2, NCH><<<gR, b512, 0, stream>>>(part, zpart, nullptr, out);
  };

  const size_t need128 =
      ((size_t)128 * 32768 + 128ul * 2048 + 32768) * 4 + (WBF_US + XB_US) * 2;
  const size_t need64 =
      ((size_t)64 * 32768 + 64ul * 2048 + 32768) * 4 + (WBF_US + XB_US) * 2;
  (void)need64;

  if (ws_size >= need128) runM(std::integral_constant<int, 128>{});
  else                    runM(std::integral_constant<int, 64>{});
}